// Round 1
// baseline (478.219 us; speedup 1.0000x reference)
//
#include <hip/hip_runtime.h>
#include <hip/hip_bf16.h>

// LieTransport: bilinear grid_sample (border pad, align_corners=False) of
// h_prev [B,C,H,W,R] with grid = base_grid - flow*dt, flow shared across C,R.
// Output layout identical to input: [B, C, H, W, R], fp32.
//
// Strategy: memory-bound. One block per output pixel (b,y,x); 256 threads
// cover C*R = 1024 floats as 256 float4 lanes (R=64 innermost => contiguous).
// Coordinate math is recomputed per-thread (wave-uniform, cheap; flow loads
// broadcast from L1).

constexpr int B = 4, C = 16, H = 128, W = 128, R = 64;
constexpr int R4 = R / 4; // float4 groups per pixel-channel

__global__ __launch_bounds__(256) void lie_transport_kernel(
    const float* __restrict__ h,     // [B,C,H,W,R]
    const float* __restrict__ flow,  // [B,2,H,W]
    const float* __restrict__ dt,    // [B]
    float* __restrict__ out)         // [B,C,H,W,R]
{
    const int pix = blockIdx.x;          // b*H*W + y*W + x  (H*W = 16384)
    const int b  = pix >> 14;
    const int yx = pix & 16383;
    const int y  = yx >> 7;
    const int x  = yx & 127;

    // ---- per-pixel sampling coords (wave-uniform) ----
    const float dtb = dt[b];
    const float fx = flow[((b * 2 + 0) * H + y) * W + x];
    const float fy = flow[((b * 2 + 1) * H + y) * W + x];

    // base grid: linspace(-1,1,W)[x] = -1 + 2*x/(W-1)
    const float gx = (-1.0f + 2.0f * (float)x / (float)(W - 1)) - fx * dtb;
    const float gy = (-1.0f + 2.0f * (float)y / (float)(H - 1)) - fy * dtb;

    // unnormalize (align_corners=False) then border-clip
    float xs = ((gx + 1.0f) * (float)W - 1.0f) * 0.5f;
    float ys = ((gy + 1.0f) * (float)H - 1.0f) * 0.5f;
    xs = fminf(fmaxf(xs, 0.0f), (float)(W - 1));
    ys = fminf(fmaxf(ys, 0.0f), (float)(H - 1));

    const float x0f = floorf(xs);
    const float y0f = floorf(ys);
    const float wx = xs - x0f;
    const float wy = ys - y0f;
    const int x0 = (int)x0f;
    const int y0 = (int)y0f;
    const int x1 = min(x0 + 1, W - 1);
    const int y1 = min(y0 + 1, H - 1);

    // ---- gather + blend: thread t -> (c = t/16, r4 = t%16) ----
    const int t  = threadIdx.x;
    const int c  = t >> 4;
    const int r4 = t & 15;

    const float4* __restrict__ h4 = (const float4*)h;
    float4* __restrict__ o4 = (float4*)out;

    const int planeBase = (b * C + c) * H; // row index into [.., H, W, R4]

    const int i00 = ((planeBase + y0) * W + x0) * R4 + r4;
    const int i01 = ((planeBase + y0) * W + x1) * R4 + r4;
    const int i10 = ((planeBase + y1) * W + x0) * R4 + r4;
    const int i11 = ((planeBase + y1) * W + x1) * R4 + r4;

    const float4 v00 = h4[i00];
    const float4 v01 = h4[i01];
    const float4 v10 = h4[i10];
    const float4 v11 = h4[i11];

    const float w1mx = 1.0f - wx;
    const float w1my = 1.0f - wy;

    float4 r;
    r.x = (v00.x * w1mx + v01.x * wx) * w1my + (v10.x * w1mx + v11.x * wx) * wy;
    r.y = (v00.y * w1mx + v01.y * wx) * w1my + (v10.y * w1mx + v11.y * wx) * wy;
    r.z = (v00.z * w1mx + v01.z * wx) * w1my + (v10.z * w1mx + v11.z * wx) * wy;
    r.w = (v00.w * w1mx + v01.w * wx) * w1my + (v10.w * w1mx + v11.w * wx) * wy;

    o4[((planeBase + y) * W + x) * R4 + r4] = r;
}

extern "C" void kernel_launch(void* const* d_in, const int* in_sizes, int n_in,
                              void* d_out, int out_size, void* d_ws, size_t ws_size,
                              hipStream_t stream) {
    const float* h_prev = (const float*)d_in[0]; // [4,16,128,128,64]
    const float* flow   = (const float*)d_in[1]; // [4,2,128,128]
    const float* dt     = (const float*)d_in[2]; // [4]
    float* out = (float*)d_out;

    const int nblocks = B * H * W; // 65536 pixels
    lie_transport_kernel<<<nblocks, 256, 0, stream>>>(h_prev, flow, dt, out);
}

// Round 2
// 468.821 us; speedup vs baseline: 1.0200x; 1.0200x over previous
//
#include <hip/hip_runtime.h>
#include <hip/hip_bf16.h>

// LieTransport: bilinear grid_sample (border pad, align_corners=False) of
// h_prev [B,C,H,W,R] with grid = base_grid - flow*dt, flow shared across C,R.
// Output layout identical to input: [B, C, H, W, R], fp32.
//
// Round 2: XCD-aware block swizzle. Blocks are dispatched round-robin across
// the 8 XCDs (blockIdx % 8); without swizzle, spatially adjacent pixels land
// on different XCDs and the bilinear-gather reuse (shared source columns/rows
// between neighboring output pixels) misses the non-shared per-XCD L2s
// (measured 1.57x read amplification: FETCH 421 MB vs 268 MB ideal).
// Swizzle gives each XCD a contiguous 64-row slab so the ~1 MB two-row reuse
// window stays resident in its 4 MiB L2.

constexpr int B = 4, C = 16, H = 128, W = 128, R = 64;
constexpr int R4 = R / 4;        // float4 groups per pixel-channel
constexpr int NPIX = B * H * W;  // 65536
constexpr int NXCD = 8;
constexpr int SLAB = NPIX / NXCD; // 8192 pixels = 64 rows per XCD slab

__global__ __launch_bounds__(256) void lie_transport_kernel(
    const float* __restrict__ h,     // [B,C,H,W,R]
    const float* __restrict__ flow,  // [B,2,H,W]
    const float* __restrict__ dt,    // [B]
    float* __restrict__ out)         // [B,C,H,W,R]
{
    // XCD-aware swizzle: hardware assigns workgroup -> XCD as blockIdx % 8.
    // Map XCD k to contiguous pixel slab [k*8192, (k+1)*8192).
    const int raw  = blockIdx.x;
    const int pix  = (raw & (NXCD - 1)) * SLAB + (raw >> 3);

    const int b  = pix >> 14;
    const int yx = pix & 16383;
    const int y  = yx >> 7;
    const int x  = yx & 127;

    // ---- per-pixel sampling coords (wave-uniform) ----
    const float dtb = dt[b];
    const float fx = flow[((b * 2 + 0) * H + y) * W + x];
    const float fy = flow[((b * 2 + 1) * H + y) * W + x];

    // base grid: linspace(-1,1,W)[x] = -1 + 2*x/(W-1)
    const float gx = (-1.0f + 2.0f * (float)x / (float)(W - 1)) - fx * dtb;
    const float gy = (-1.0f + 2.0f * (float)y / (float)(H - 1)) - fy * dtb;

    // unnormalize (align_corners=False) then border-clip
    float xs = ((gx + 1.0f) * (float)W - 1.0f) * 0.5f;
    float ys = ((gy + 1.0f) * (float)H - 1.0f) * 0.5f;
    xs = fminf(fmaxf(xs, 0.0f), (float)(W - 1));
    ys = fminf(fmaxf(ys, 0.0f), (float)(H - 1));

    const float x0f = floorf(xs);
    const float y0f = floorf(ys);
    const float wx = xs - x0f;
    const float wy = ys - y0f;
    const int x0 = (int)x0f;
    const int y0 = (int)y0f;
    const int x1 = min(x0 + 1, W - 1);
    const int y1 = min(y0 + 1, H - 1);

    // ---- gather + blend: thread t -> (c = t/16, r4 = t%16) ----
    const int t  = threadIdx.x;
    const int c  = t >> 4;
    const int r4 = t & 15;

    const float4* __restrict__ h4 = (const float4*)h;
    float4* __restrict__ o4 = (float4*)out;

    const int planeBase = (b * C + c) * H; // row index into [.., H, W, R4]

    const int i00 = ((planeBase + y0) * W + x0) * R4 + r4;
    const int i01 = ((planeBase + y0) * W + x1) * R4 + r4;
    const int i10 = ((planeBase + y1) * W + x0) * R4 + r4;
    const int i11 = ((planeBase + y1) * W + x1) * R4 + r4;

    const float4 v00 = h4[i00];
    const float4 v01 = h4[i01];
    const float4 v10 = h4[i10];
    const float4 v11 = h4[i11];

    const float w1mx = 1.0f - wx;
    const float w1my = 1.0f - wy;

    float4 r;
    r.x = (v00.x * w1mx + v01.x * wx) * w1my + (v10.x * w1mx + v11.x * wx) * wy;
    r.y = (v00.y * w1mx + v01.y * wx) * w1my + (v10.y * w1mx + v11.y * wx) * wy;
    r.z = (v00.z * w1mx + v01.z * wx) * w1my + (v10.z * w1mx + v11.z * wx) * wy;
    r.w = (v00.w * w1mx + v01.w * wx) * w1my + (v10.w * w1mx + v11.w * wx) * wy;

    o4[((planeBase + y) * W + x) * R4 + r4] = r;
}

extern "C" void kernel_launch(void* const* d_in, const int* in_sizes, int n_in,
                              void* d_out, int out_size, void* d_ws, size_t ws_size,
                              hipStream_t stream) {
    const float* h_prev = (const float*)d_in[0]; // [4,16,128,128,64]
    const float* flow   = (const float*)d_in[1]; // [4,2,128,128]
    const float* dt     = (const float*)d_in[2]; // [4]
    float* out = (float*)d_out;

    lie_transport_kernel<<<NPIX, 256, 0, stream>>>(h_prev, flow, dt, out);
}